// Round 6
// baseline (154.227 us; speedup 1.0000x reference)
//
#include <hip/hip_runtime.h>
#include <hip/hip_bf16.h>

// B=64, T=4096, Feat=32, Ch=16; kernel (3,32,1,16), Hp=14, Wp=1, F=16.
// out[bt,hp,f] = relu((conv + bias[f])*sc[t] + sh[t]),  t = bt % 4096
// conv[(bt,hp),f] = sum_{i<3,j<32} x[bt,j,hp+i] * k[i,j,f]
// R6: persistent 4-tile blocks. Per tile: {write LDS from prefetched regs;
// bar; prefetch next tile (global->reg, hides under compute); compute; bar}.
// Weights staged once/block; BN params via LDS; cvt via __float2bfloat16
// (compiler emits v_cvt_pk_bf16_f32). Swapped-operand MFMA as R5.

typedef __attribute__((ext_vector_type(8))) short bf16x8;
typedef __attribute__((ext_vector_type(4))) float f32x4;

#define NBT 16               // bt per tile (4 waves * 4 bt)
#define TPT 4                // tiles per block
#define XSTRIDE 40           // bf16 per xT row: 32 + 8 pad (80 B)
#define XTILE (18 * XSTRIDE + 8)   // 728 bf16 per bt tile
#define WSTRIDE 104          // bf16 per BwT row: 96 + 8 pad

__device__ __forceinline__ unsigned short f2bf(float f) {
    __hip_bfloat16 h = __float2bfloat16(f);
    unsigned short s; __builtin_memcpy(&s, &h, 2); return s;
}
__device__ __forceinline__ unsigned pack2(float a, float b) {
    return (unsigned)f2bf(a) | ((unsigned)f2bf(b) << 16);
}

__global__ __launch_bounds__(256, 4) void tccnn_mfma(
    const float* __restrict__ x,      // (B*T, 32, 16)
    const float* __restrict__ kern,   // (3,32,1,16) = 1536
    const float* __restrict__ bias,   // (16,)
    const float* __restrict__ gamma,  // (4096,)
    const float* __restrict__ beta,   // (4096,)
    const float* __restrict__ mmean,  // (4096,)
    const float* __restrict__ mvar,   // (4096,)
    float* __restrict__ out)          // (B*T, 14, 16)
{
    __shared__ __align__(16) unsigned short xs[NBT * XTILE];    // 23296 B
    __shared__ __align__(16) unsigned short wsh[16 * WSTRIDE];  // 3328 B
    __shared__ __align__(16) float scs[NBT], shs[NBT];          // 128 B

    const int tid = threadIdx.x;
    long btbase = (long)blockIdx.x * (NBT * TPT);

    // ---- stage weights once: BwT[f][k=i*32+j] bf16 ----
    #pragma unroll
    for (int v = 0; v < 6; ++v) {
        int idx = v * 256 + tid;
        int ij = idx >> 4, f = idx & 15;
        wsh[f * WSTRIDE + ij] = f2bf(kern[idx]);
    }

    const int u = tid & 15, btl_s = tid >> 4;     // staging decomposition
    const int cu = u & 3, ju = u >> 2;            // c0 = cu*4, j0 = ju*8

    // ---- prefetch tile 0 (x -> regs, BN -> regs) ----
    float4 rr[8];
    {
        const float4* src = (const float4*)(x + (btbase + btl_s) * 512 + ju * 128 + cu * 4);
        #pragma unroll
        for (int k = 0; k < 8; ++k) rr[k] = src[k * 4];
    }
    float bn_g = 0.f, bn_b = 0.f, bn_m = 0.f, bn_v = 0.f;
    if (tid < 16) {
        int t = (int)((btbase + tid) & 4095);
        bn_g = gamma[t]; bn_b = beta[t]; bn_m = mmean[t]; bn_v = mvar[t];
    }

    __syncthreads();                               // weights visible

    const int lane = tid & 63, wv = tid >> 6;
    const int hp = lane & 15;                      // C col = hp
    const int g = lane >> 4;                       // C rows f = g*4+r

    const bf16x8 bfr0 = *(const bf16x8*)&wsh[hp * WSTRIDE + 0 * 32 + g * 8];
    const bf16x8 bfr1 = *(const bf16x8*)&wsh[hp * WSTRIDE + 1 * 32 + g * 8];
    const bf16x8 bfr2 = *(const bf16x8*)&wsh[hp * WSTRIDE + 2 * 32 + g * 8];
    const float4 b4 = *(const float4*)&bias[g * 4];

    for (int tt = 0; tt < TPT; ++tt) {
        // ---- write phase: BN params + transposed x tile into LDS ----
        if (tid < 16) {
            float sc = bn_g * rsqrtf(bn_v + 1e-3f);
            scs[tid] = sc;
            shs[tid] = bn_b - bn_m * sc;
        }
        {
            unsigned short* dst = &xs[btl_s * XTILE + ju * 8];
            *(uint4*)&dst[(cu * 4 + 0) * XSTRIDE] = make_uint4(
                pack2(rr[0].x, rr[1].x), pack2(rr[2].x, rr[3].x),
                pack2(rr[4].x, rr[5].x), pack2(rr[6].x, rr[7].x));
            *(uint4*)&dst[(cu * 4 + 1) * XSTRIDE] = make_uint4(
                pack2(rr[0].y, rr[1].y), pack2(rr[2].y, rr[3].y),
                pack2(rr[4].y, rr[5].y), pack2(rr[6].y, rr[7].y));
            *(uint4*)&dst[(cu * 4 + 2) * XSTRIDE] = make_uint4(
                pack2(rr[0].z, rr[1].z), pack2(rr[2].z, rr[3].z),
                pack2(rr[4].z, rr[5].z), pack2(rr[6].z, rr[7].z));
            *(uint4*)&dst[(cu * 4 + 3) * XSTRIDE] = make_uint4(
                pack2(rr[0].w, rr[1].w), pack2(rr[2].w, rr[3].w),
                pack2(rr[4].w, rr[5].w), pack2(rr[6].w, rr[7].w));
        }
        __syncthreads();

        // ---- prefetch next tile (hides under compute below) ----
        if (tt + 1 < TPT) {
            const float4* src = (const float4*)(x + (btbase + NBT + btl_s) * 512 + ju * 128 + cu * 4);
            #pragma unroll
            for (int k = 0; k < 8; ++k) rr[k] = src[k * 4];
            if (tid < 16) {
                int t = (int)((btbase + NBT + tid) & 4095);
                bn_g = gamma[t]; bn_b = beta[t]; bn_m = mmean[t]; bn_v = mvar[t];
            }
        }

        // ---- compute: wave owns 4 bts; 3 MFMAs each ----
        const float4 sc4 = *(const float4*)&scs[wv * 4];
        const float4 sh4 = *(const float4*)&shs[wv * 4];
        const float scq[4] = {sc4.x, sc4.y, sc4.z, sc4.w};
        const float shq[4] = {sh4.x, sh4.y, sh4.z, sh4.w};

        #pragma unroll
        for (int q = 0; q < 4; ++q) {
            const int btl = wv * 4 + q;
            const unsigned short* xt = &xs[btl * XTILE];
            bf16x8 a0 = *(const bf16x8*)&xt[(hp + 0) * XSTRIDE + g * 8];
            bf16x8 a1 = *(const bf16x8*)&xt[(hp + 1) * XSTRIDE + g * 8];
            bf16x8 a2 = *(const bf16x8*)&xt[(hp + 2) * XSTRIDE + g * 8];

            f32x4 acc = {0.f, 0.f, 0.f, 0.f};
            acc = __builtin_amdgcn_mfma_f32_16x16x32_bf16(bfr0, a0, acc, 0, 0, 0);
            acc = __builtin_amdgcn_mfma_f32_16x16x32_bf16(bfr1, a1, acc, 0, 0, 0);
            acc = __builtin_amdgcn_mfma_f32_16x16x32_bf16(bfr2, a2, acc, 0, 0, 0);

            const float sc = scq[q], sh = shq[q];
            if (hp < 14) {
                float4 y;
                y.x = fmaxf((acc[0] + b4.x) * sc + sh, 0.f);
                y.y = fmaxf((acc[1] + b4.y) * sc + sh, 0.f);
                y.z = fmaxf((acc[2] + b4.z) * sc + sh, 0.f);
                y.w = fmaxf((acc[3] + b4.w) * sc + sh, 0.f);
                *(float4*)(out + (btbase + btl) * 224 + hp * 16 + g * 4) = y;
            }
        }
        __syncthreads();
        btbase += NBT;
    }
}

extern "C" void kernel_launch(void* const* d_in, const int* in_sizes, int n_in,
                              void* d_out, int out_size, void* d_ws, size_t ws_size,
                              hipStream_t stream) {
    const float* x     = (const float*)d_in[0];
    const float* kern  = (const float*)d_in[1];
    const float* bias  = (const float*)d_in[2];
    const float* gamma = (const float*)d_in[3];
    const float* beta  = (const float*)d_in[4];
    const float* mmean = (const float*)d_in[5];
    const float* mvar  = (const float*)d_in[6];
    float* out = (float*)d_out;

    const int n_bt = 64 * 4096;                    // 262144
    const int blocks = n_bt / (NBT * TPT);         // 4096
    tccnn_mfma<<<blocks, 256, 0, stream>>>(x, kern, bias, gamma, beta,
                                           mmean, mvar, out);
}

// Round 8
// 137.590 us; speedup vs baseline: 1.1209x; 1.1209x over previous
//
#include <hip/hip_runtime.h>
#include <hip/hip_bf16.h>

// B=64, T=4096, Feat=32, Ch=16; kernel (3,32,1,16), Hp=14, Wp=1, F=16.
// out[bt,hp,f] = relu((conv + bias[f])*sc[t] + sh[t]),  t = bt % 4096
// conv[(bt,hp),f] = sum_{i<3,j<32} x[bt,j,hp+i] * k[i,j,f]
// R8 = R7 with native clang vector types for the nontemporal builtins
// (HIP_vector_type float4 is rejected by __builtin_nontemporal_*).
// R5 structure: 16 bt/block, swapped-operand MFMA (C col=hp, rows f) ->
// one predicated float4-equivalent nt store per bt.

typedef __attribute__((ext_vector_type(8))) short bf16x8;
typedef __attribute__((ext_vector_type(4))) float f32x4;
typedef __attribute__((ext_vector_type(4))) unsigned int u32x4;

#define NBT 16               // bt tiles per block (4 waves * 4 bt)
#define XSTRIDE 40           // bf16 per xT row: 32 + 8 pad (80 B, 16B-aligned)
#define XTILE (18 * XSTRIDE + 8)   // 728 bf16 per bt tile
#define WSTRIDE 104          // bf16 per BwT row: 96 + 8 pad (208 B)

__device__ __forceinline__ unsigned short f2bf(float f) {
    unsigned u = __builtin_bit_cast(unsigned, f);
    return (unsigned short)((u + 0x7fffu + ((u >> 16) & 1u)) >> 16);  // RNE
}
__device__ __forceinline__ unsigned pack2(float a, float b) {
    return (unsigned)f2bf(a) | ((unsigned)f2bf(b) << 16);
}

__global__ __launch_bounds__(256) void tccnn_mfma(
    const float* __restrict__ x,      // (B*T, 32, 16)
    const float* __restrict__ kern,   // (3,32,1,16) = 1536
    const float* __restrict__ bias,   // (16,)
    const float* __restrict__ gamma,  // (4096,)
    const float* __restrict__ beta,   // (4096,)
    const float* __restrict__ mmean,  // (4096,)
    const float* __restrict__ mvar,   // (4096,)
    float* __restrict__ out)          // (B*T, 14, 16)
{
    __shared__ __align__(16) unsigned short xs[NBT * XTILE];    // 23296 B
    __shared__ __align__(16) unsigned short wsh[16 * WSTRIDE];  // 3328 B

    const int tid = threadIdx.x;
    const long bt0 = (long)blockIdx.x * NBT;

    // ---- stage weights as BwT[f][k=i*32+j] bf16 (1536 floats, 6/thread) ----
    #pragma unroll
    for (int v = 0; v < 6; ++v) {
        int idx = v * 256 + tid;
        int ij = idx >> 4, f = idx & 15;
        wsh[f * WSTRIDE + ij] = f2bf(kern[idx]);
    }

    // ---- stage x transposed: xT[c][j] bf16. Unit = 4c x 8j; 256 units,
    //      1/thread. 8x nontemporal 16B loads -> 4x ds_write_b128. ----
    {
        int U = tid;
        int btl = U >> 4, u = U & 15;
        int cu = u & 3, ju = u >> 2;              // c0 = cu*4, j0 = ju*8
        const f32x4* src = (const f32x4*)(x + (bt0 + btl) * 512 + ju * 128 + cu * 4);
        f32x4 r0 = __builtin_nontemporal_load(src + 0);
        f32x4 r1 = __builtin_nontemporal_load(src + 4);
        f32x4 r2 = __builtin_nontemporal_load(src + 8);
        f32x4 r3 = __builtin_nontemporal_load(src + 12);
        f32x4 r4 = __builtin_nontemporal_load(src + 16);
        f32x4 r5 = __builtin_nontemporal_load(src + 20);
        f32x4 r6 = __builtin_nontemporal_load(src + 24);
        f32x4 r7 = __builtin_nontemporal_load(src + 28);
        unsigned short* dst = &xs[btl * XTILE + ju * 8];
        *(uint4*)&dst[(cu * 4 + 0) * XSTRIDE] = make_uint4(
            pack2(r0.x, r1.x), pack2(r2.x, r3.x), pack2(r4.x, r5.x), pack2(r6.x, r7.x));
        *(uint4*)&dst[(cu * 4 + 1) * XSTRIDE] = make_uint4(
            pack2(r0.y, r1.y), pack2(r2.y, r3.y), pack2(r4.y, r5.y), pack2(r6.y, r7.y));
        *(uint4*)&dst[(cu * 4 + 2) * XSTRIDE] = make_uint4(
            pack2(r0.z, r1.z), pack2(r2.z, r3.z), pack2(r4.z, r5.z), pack2(r6.z, r7.z));
        *(uint4*)&dst[(cu * 4 + 3) * XSTRIDE] = make_uint4(
            pack2(r0.w, r1.w), pack2(r2.w, r3.w), pack2(r4.w, r5.w), pack2(r6.w, r7.w));
    }
    __syncthreads();

    // ---- compute: wave owns 4 bts; 3 MFMAs each (swapped operands) ----
    const int lane = tid & 63;
    const int wv = tid >> 6;
    const int hp = lane & 15;                      // C col = hp
    const int g = lane >> 4;                       // k-group; C rows f=g*4+r

    // A-operand (weights): lane provides BwT[f=lane&15][k=g*8+jj]
    bf16x8 bfr0 = *(const bf16x8*)&wsh[hp * WSTRIDE + 0 * 32 + g * 8];
    bf16x8 bfr1 = *(const bf16x8*)&wsh[hp * WSTRIDE + 1 * 32 + g * 8];
    bf16x8 bfr2 = *(const bf16x8*)&wsh[hp * WSTRIDE + 2 * 32 + g * 8];
    const float4 b4 = *(const float4*)&bias[g * 4]; // bias[f], f = g*4+r

    #pragma unroll
    for (int q = 0; q < 4; ++q) {
        const int btl = wv * 4 + q;
        const unsigned short* xt = &xs[btl * XTILE];
        // B-operand: lane provides xT[(lane&15)+i][k=g*8+jj]
        bf16x8 a0 = *(const bf16x8*)&xt[(hp + 0) * XSTRIDE + g * 8];
        bf16x8 a1 = *(const bf16x8*)&xt[(hp + 1) * XSTRIDE + g * 8];
        bf16x8 a2 = *(const bf16x8*)&xt[(hp + 2) * XSTRIDE + g * 8];

        f32x4 acc = {0.f, 0.f, 0.f, 0.f};
        acc = __builtin_amdgcn_mfma_f32_16x16x32_bf16(bfr0, a0, acc, 0, 0, 0);
        acc = __builtin_amdgcn_mfma_f32_16x16x32_bf16(bfr1, a1, acc, 0, 0, 0);
        acc = __builtin_amdgcn_mfma_f32_16x16x32_bf16(bfr2, a2, acc, 0, 0, 0);

        const long bt = bt0 + btl;
        const int t = (int)(bt & 4095);
        const float sc = gamma[t] * rsqrtf(mvar[t] + 1e-3f);
        const float sh = beta[t] - mmean[t] * sc;

        if (hp < 14) {
            f32x4 y;
            y.x = fmaxf((acc[0] + b4.x) * sc + sh, 0.f);
            y.y = fmaxf((acc[1] + b4.y) * sc + sh, 0.f);
            y.z = fmaxf((acc[2] + b4.z) * sc + sh, 0.f);
            y.w = fmaxf((acc[3] + b4.w) * sc + sh, 0.f);
            __builtin_nontemporal_store(y, (f32x4*)(out + bt * 224 + hp * 16 + g * 4));
        }
    }
}

extern "C" void kernel_launch(void* const* d_in, const int* in_sizes, int n_in,
                              void* d_out, int out_size, void* d_ws, size_t ws_size,
                              hipStream_t stream) {
    const float* x     = (const float*)d_in[0];
    const float* kern  = (const float*)d_in[1];
    const float* bias  = (const float*)d_in[2];
    const float* gamma = (const float*)d_in[3];
    const float* beta  = (const float*)d_in[4];
    const float* mmean = (const float*)d_in[5];
    const float* mvar  = (const float*)d_in[6];
    float* out = (float*)d_out;

    const int n_bt = 64 * 4096;                    // 262144
    const int blocks = n_bt / NBT;                 // 16384
    tccnn_mfma<<<blocks, 256, 0, stream>>>(x, kern, bias, gamma, beta,
                                           mmean, mvar, out);
}